// Round 15
// baseline (5251.583 us; speedup 1.0000x reference)
//
#include <hip/hip_runtime.h>
#include <hip/hip_bf16.h>
#include <stdint.h>

typedef unsigned long long u64;
typedef uint32_t u32;
typedef __attribute__((ext_vector_type(8))) short bf16x8;
typedef __attribute__((ext_vector_type(4))) float f32x4;

// RTRBM CD-k step. Exact JAX-threefry; f64 where sample margins demand it;
// bf16-pair MFMA fast paths + f64 boundary fixups for all sampling GEMMs.
#define NV 1024
#define NH 512
#define TT 128
#define BB 256
#define TBsz (TT*BB)          // 32768
#define HTBsz (NH*TBsz)       // 16777216
#define VTBsz (NV*TBsz)       // 33554432
#define NWV (NV/64)           // 16
#define NWH (NH/64)           // 8
#define QCAP 1048576u
#define DELTA 5e-4
#define BSTv 528              // kvisM LDS col stride (ushorts), bank-padded
#define BSTh 528              // khidM LDS col stride

// ---------------- Threefry-2x32 (JAX exact) ----------------
__host__ __device__ inline void tf2x32(uint32_t k0, uint32_t k1,
                                       uint32_t x0, uint32_t x1,
                                       uint32_t& o0, uint32_t& o1) {
  const uint32_t ks2 = k0 ^ k1 ^ 0x1BD11BDAu;
#define ROTL(x,d) (((x)<<(d))|((x)>>(32-(d))))
#define RND(r) { x0 += x1; x1 = ROTL(x1,r); x1 ^= x0; }
  x0 += k0;  x1 += k1;
  RND(13) RND(15) RND(26) RND(6)
  x0 += k1;  x1 += ks2 + 1u;
  RND(17) RND(29) RND(16) RND(24)
  x0 += ks2; x1 += k0 + 2u;
  RND(13) RND(15) RND(26) RND(6)
  x0 += k0;  x1 += k1 + 3u;
  RND(17) RND(29) RND(16) RND(24)
  x0 += k1;  x1 += ks2 + 4u;
  RND(13) RND(15) RND(26) RND(6)
  x0 += ks2; x1 += k0 + 5u;
  o0 = x0; o1 = x1;
#undef RND
#undef ROTL
}

__device__ inline double tf_uniform64(uint32_t k0, uint32_t k1, uint32_t i) {
  uint32_t o0, o1;
  tf2x32(k0, k1, 0u, i, o0, o1);
  uint32_t bits = o0 ^ o1;
  uint32_t fb = (bits >> 9) | 0x3f800000u;
  float f = __uint_as_float(fb) - 1.0f;
  return (double)f;
}

__device__ inline double sigmoid64(double x) { return 1.0 / (1.0 + exp(-x)); }

__device__ inline void bfsplit(float w, ushort& b1o, ushort& b2o) {
  __hip_bfloat16 b1 = __float2bfloat16(w);
  float r = w - __bfloat162float(b1);
  __hip_bfloat16 b2 = __float2bfloat16(r);
  b1o = *reinterpret_cast<ushort*>(&b1);
  b2o = *reinterpret_cast<ushort*>(&b2);
}

// ------- fused W preps: W64 (f64 copy) + kvisM frags + khidM frags --------------
__global__ __launch_bounds__(256) void kprepWall(const float* __restrict__ W,
                                                 double* __restrict__ W64,
                                                 ushort* __restrict__ A1,
                                                 ushort* __restrict__ A2,
                                                 ushort* __restrict__ AW1,
                                                 ushort* __restrict__ AW2) {
  int idx = blockIdx.x * 256 + threadIdx.x;     // 524288
  W64[idx] = (double)W[idx];
  {  // kvisM: W^T fragments (row=v, k=h)
    int i    = idx & 7;
    int lane = (idx >> 3) & 63;
    int ks   = (idx >> 9) & 15;
    int vt   = idx >> 13;
    int h = ks*32 + ((lane >> 4) << 3) + i;
    int v = vt*16 + (lane & 15);
    bfsplit(W[(size_t)h*NV + v], A1[idx], A2[idx]);
  }
  {  // khidM: W fragments (row=h, k=v)
    int i    = idx & 7;
    int lane = (idx >> 3) & 63;
    int kt   = (idx >> 9) & 31;
    int ht   = idx >> 14;
    int h = ht*16 + (lane & 15);
    int v = kt*32 + ((lane >> 4) << 3) + i;
    bfsplit(W[(size_t)h*NV + v], AW1[idx], AW2[idx]);
  }
}

// ------- fused U preps: U64 + UB (blocked) + khidM AU frags ---------------------
__global__ __launch_bounds__(256) void kprepUall(const float* __restrict__ U,
                                                 double* __restrict__ U64,
                                                 float4* __restrict__ UB,
                                                 ushort* __restrict__ AU1,
                                                 ushort* __restrict__ AU2) {
  int idx = blockIdx.x * 256 + threadIdx.x;     // 262144
  U64[idx] = (double)U[idx];
  {  // AU fragments (row=h, k=r)
    int i    = idx & 7;
    int lane = (idx >> 3) & 63;
    int kt   = (idx >> 9) & 15;
    int ht   = idx >> 13;
    int h = ht*16 + (lane & 15);
    int r = kt*32 + ((lane >> 4) << 3) + i;
    bfsplit(U[(size_t)h*NH + r], AU1[idx], AU2[idx]);
  }
  if (idx < NH*NH/4) {  // UB[r4*NH + h]
    int r4 = idx / NH;
    int h  = idx % NH;
    const float* __restrict__ p = U + (size_t)h*NH + r4*4;
    UB[idx] = make_float4(p[0], p[1], p[2], p[3]);
  }
}

// ---------------- bit-pack v_data: f32 [NV][TBsz] -> u64 [TBsz][NWV] -----------
__global__ __launch_bounds__(256) void kpack_f32(const float* __restrict__ in,
                                                 u64* __restrict__ out) {
  int bw = blockIdx.x >> 7;                    // 0..15
  int tb = (blockIdx.x & 127) * 256 + threadIdx.x;
  u64 m = 0;
  #pragma unroll 8
  for (int j = 0; j < 64; ++j)
    m |= (u64)(in[(size_t)(bw*64 + j)*TBsz + tb] != 0.0f ? 1 : 0) << j;
  out[(size_t)tb*NWV + bw] = m;
}

// ------- WvT[(t*BB+b)*NH + h] = sum_v W[h,v]*vbit  (f64, broadcast W, TBM=2) ---
// Block covers t-pair (t, t+64) with the same h-group: each uniform W load
// feeds 4 FMA (2 tb x 2 v). Per-output accumulation chain identical to R12/R14.
__global__ __launch_bounds__(256) void kWv(const u64* __restrict__ vb,
                                           const double* __restrict__ W64,
                                           double* __restrict__ WvT) {
  const int HM = 8;
  int tpair = blockIdx.x / (NH/HM);            // 0..63
  int h0 = (blockIdx.x % (NH/HM)) * HM;
  int tbA = tpair*BB + threadIdx.x;
  int tbB = (tpair + TT/2)*BB + threadIdx.x;
  u64 mA[NWV], mB[NWV];
  #pragma unroll
  for (int w = 0; w < NWV; ++w) mA[w] = vb[(size_t)tbA*NWV + w];
  #pragma unroll
  for (int w = 0; w < NWV; ++w) mB[w] = vb[(size_t)tbB*NWV + w];
  double accA[HM], accB[HM];
  #pragma unroll
  for (int i = 0; i < HM; ++i) { accA[i] = 0.0; accB[i] = 0.0; }
  const double2* __restrict__ W2 = (const double2*)W64;
  for (int w = 0; w < NWV; ++w) {
    u64 mwA = mA[w], mwB = mB[w];
    #pragma unroll 8
    for (int j2 = 0; j2 < 32; ++j2) {
      double bdA0 = (double)((unsigned)((mwA >> (2*j2+0)) & 1ull));
      double bdA1 = (double)((unsigned)((mwA >> (2*j2+1)) & 1ull));
      double bdB0 = (double)((unsigned)((mwB >> (2*j2+0)) & 1ull));
      double bdB1 = (double)((unsigned)((mwB >> (2*j2+1)) & 1ull));
      int vi = w*32 + j2;
      #pragma unroll
      for (int i = 0; i < HM; ++i) {
        double2 wv = W2[(size_t)(h0+i)*(NV/2) + vi];
        accA[i] = fma(bdA0, wv.x, accA[i]);
        accA[i] = fma(bdA1, wv.y, accA[i]);
        accB[i] = fma(bdB0, wv.x, accB[i]);
        accB[i] = fma(bdB1, wv.y, accB[i]);
      }
    }
  }
  #pragma unroll
  for (int i = 0; i < HM; ++i) {
    WvT[(size_t)tbA*NH + h0 + i] = accA[i];
    WvT[(size_t)tbB*NH + h0 + i] = accB[i];
  }
}

// ---------------- fused recurrence (R8-proven): 256 blocks x 512 thr ------------
__global__ __launch_bounds__(512) void krecur(const double* __restrict__ WvT,
                                              const float4* __restrict__ UB,
                                              const float* __restrict__ bh,
                                              const float* __restrict__ binit,
                                              double* __restrict__ rT) {
  __shared__ double rA[2][NH];
  const int b = blockIdx.x;
  const int h = threadIdx.x;
  const double bhd = (double)bh[h];
  double p = sigmoid64(WvT[(size_t)b*NH + h] + (double)binit[h]);
  rA[0][h] = p;
  rT[(size_t)b*NH + h] = p;
  __syncthreads();
  int cur = 0;
  for (int t = 1; t < TT; ++t) {
    double acc = WvT[((size_t)t*BB + b)*NH + h];
    double a0=0, a1=0, a2=0, a3=0;
    const double2* __restrict__ rA2 = (const double2*)rA[cur];
    #pragma unroll 4
    for (int r = 0; r < NH; r += 4) {
      float4 u4 = UB[(size_t)(r >> 2)*NH + h];
      double2 q01 = rA2[(r>>1)+0];
      double2 q23 = rA2[(r>>1)+1];
      a0 = fma((double)u4.x, q01.x, a0);
      a1 = fma((double)u4.y, q01.y, a1);
      a2 = fma((double)u4.z, q23.x, a2);
      a3 = fma((double)u4.w, q23.y, a3);
    }
    p = sigmoid64((acc + ((a0+a1)+(a2+a3))) + bhd);
    rA[cur ^ 1][h] = p;
    rT[((size_t)t*BB + b)*NH + h] = p;
    __syncthreads();
    cur ^= 1;
  }
}

// ------ transpose rT -> out_r f32, fused h1 = bernoulli(sk, r) ------------------
__global__ __launch_bounds__(256) void ktrans_s(const double* __restrict__ rT,
                                                float* __restrict__ out_r,
                                                uint8_t* __restrict__ hbytes,
                                                u32 k0, u32 k1) {
  __shared__ double lds[32][33];
  int t  = blockIdx.x;
  int h0 = blockIdx.y * 32;
  int b0 = blockIdx.z * 32;
  int tx = threadIdx.x & 31;
  int ty = threadIdx.x >> 5;
  #pragma unroll
  for (int i = 0; i < 4; ++i) {
    int row = ty*4 + i;
    lds[row][tx] = rT[((size_t)t*BB + b0 + row)*NH + h0 + tx];
  }
  __syncthreads();
  #pragma unroll
  for (int i = 0; i < 4; ++i) {
    int row = ty*4 + i;
    out_r[(size_t)(h0+row)*TBsz + (size_t)t*BB + b0 + tx] = (float)lds[tx][row];
  }
  if (threadIdx.x < 128) {
    int tbr = threadIdx.x >> 2;
    int bix = threadIdx.x & 3;
    int tb  = t*BB + b0 + tbr;
    unsigned byte = 0;
    #pragma unroll
    for (int j = 0; j < 8; ++j) {
      int hrel = bix*8 + j;
      double p = lds[tbr][hrel];
      double u = tf_uniform64(k0, k1, (u32)((h0 + hrel)*TBsz + tb));
      byte |= (u < p) ? (1u << j) : 0u;
    }
    hbytes[(size_t)tb*(NH/8) + (h0 >> 3) + bix] = (uint8_t)byte;
  }
}

// -------- v-side MFMA, stage-once: grid 256 (tb-tiles of 128), loop 16 vblk -----
__global__ __launch_bounds__(256) void kvisM(
    const ushort* __restrict__ A1, const ushort* __restrict__ A2,
    const float* __restrict__ bv, const u64* __restrict__ hbits,
    u64* __restrict__ vbits, float* __restrict__ vf,
    u32* __restrict__ queue, u32* __restrict__ cnt, u32 k0, u32 k1) {
  __shared__ ushort Blds[128*BSTv];            // 132 KB (bank-padded stride)
  __shared__ u64 sbits[128];
  int tb0 = blockIdx.x * 128;
  int tid = threadIdx.x;
  // stage B once: col c, half hs; bits -> bf16 0/1, k-block XOR-swizzled
  {
    int c  = tid & 127;
    int hs = tid >> 7;                         // 0..1
    const u64* hp = hbits + (size_t)(tb0 + c)*NWH + hs*4;
    #pragma unroll
    for (int w = 0; w < 4; ++w) {
      u64 mm = hp[w];
      int kbase = hs*256 + w*64;
      #pragma unroll
      for (int j2 = 0; j2 < 32; ++j2) {
        int k = kbase + 2*j2;
        u32 val = (u32)((mm >> (2*j2)) & 1ull) * 0x3F80u
                | (u32)((mm >> (2*j2+1)) & 1ull) * 0x3F800000u;
        int blk = (k >> 3) ^ (c & 7);
        *(u32*)&Blds[c*BSTv + (blk << 3) + (k & 7)] = val;
      }
    }
  }
  __syncthreads();
  int wv = tid >> 6, l = tid & 63;
  int wr = wv >> 1, wc = wv & 1;
  for (int vblk = 0; vblk < 16; ++vblk) {
    f32x4 acc[2][4];
    #pragma unroll
    for (int m = 0; m < 2; ++m)
      #pragma unroll
      for (int n = 0; n < 4; ++n) acc[m][n] = (f32x4){0.f,0.f,0.f,0.f};
    for (int ks = 0; ks < 16; ++ks) {
      bf16x8 bf[4];
      #pragma unroll
      for (int n = 0; n < 4; ++n) {
        int col = wc*64 + n*16 + (l & 15);
        int k = ks*32 + ((l >> 4) << 3);
        int blk = (k >> 3) ^ (col & 7);
        bf[n] = *(const bf16x8*)&Blds[col*BSTv + (blk << 3)];
      }
      #pragma unroll
      for (int m = 0; m < 2; ++m) {
        int vt = vblk*4 + wr*2 + m;
        size_t abase = (((size_t)vt*16 + ks)*64 + l)*8;
        bf16x8 a1 = *(const bf16x8*)&A1[abase];
        bf16x8 a2 = *(const bf16x8*)&A2[abase];
        #pragma unroll
        for (int n = 0; n < 4; ++n) {
          acc[m][n] = __builtin_amdgcn_mfma_f32_16x16x32_bf16(a1, bf[n], acc[m][n], 0,0,0);
          acc[m][n] = __builtin_amdgcn_mfma_f32_16x16x32_bf16(a2, bf[n], acc[m][n], 0,0,0);
        }
      }
    }
    int v0 = vblk * 64;
    u64 mask[4] = {0,0,0,0};
    #pragma unroll
    for (int n = 0; n < 4; ++n) {
      int col = wc*64 + n*16 + (l & 15);
      int tb = tb0 + col;
      #pragma unroll
      for (int m = 0; m < 2; ++m) {
        #pragma unroll
        for (int r = 0; r < 4; ++r) {
          int vrel = wr*32 + m*16 + ((l >> 4) << 2) + r;
          int v = v0 + vrel;
          float p = 1.f / (1.f + __expf(-(acc[m][n][r] + bv[v])));
          size_t o = (size_t)v*TBsz + tb;
          double u = tf_uniform64(k0, k1, (u32)o);
          double diff = (double)p - u;
          unsigned smp = diff > 0.0 ? 1u : 0u;
          if (fabs(diff) < DELTA) {
            u32 s = atomicAdd(cnt, 1u);
            if (s < QCAP) queue[s] = (u32)o;
          }
          if (smp) mask[n] |= 1ull << vrel;
          if (vf) vf[o] = (float)smp;
        }
      }
    }
    if (vbits) {
      __syncthreads();
      if (tid < 128) sbits[tid] = 0;
      __syncthreads();
      #pragma unroll
      for (int n = 0; n < 4; ++n) {
        int col = wc*64 + n*16 + (l & 15);
        atomicOr(&sbits[col], mask[n]);
      }
      __syncthreads();
      if (tid < 128)
        vbits[(size_t)(tb0 + tid)*NWV + vblk] = sbits[tid];
    }
  }
}

// ---------------- h-side MFMA: O[h][tb] = W@v1 + U@r_lag ------------------------
__global__ __launch_bounds__(256) void khidM(
    const ushort* __restrict__ AW1, const ushort* __restrict__ AW2,
    const ushort* __restrict__ AU1, const ushort* __restrict__ AU2,
    const float* __restrict__ bh, const float* __restrict__ binit,
    const u64* __restrict__ vbits, const float* __restrict__ r32,
    u64* __restrict__ h2bits, u32* __restrict__ queue,
    u32* __restrict__ cnt, u32 k0, u32 k1) {
  __shared__ ushort Blds[64*BSTh];             // 66 KB
  int nblk = blockIdx.x & 511;
  int hblk = blockIdx.x >> 9;                  // 0..7
  int tb0 = nblk * 64, h0 = hblk * 64;
  int t = tb0 >> 8;
  int tid = threadIdx.x;
  int wv = tid >> 6, l = tid & 63;
  int wr = wv >> 1, wc = wv & 1;
  f32x4 acc[2][2];
  #pragma unroll
  for (int m = 0; m < 2; ++m)
    #pragma unroll
    for (int n = 0; n < 2; ++n) acc[m][n] = (f32x4){0.f,0.f,0.f,0.f};

  // ---- V phases (W @ v1bits), K chunks q=0,1
  for (int q = 0; q < 2; ++q) {
    {
      int c = tid >> 2, seg = tid & 3;
      const u64* vp = vbits + (size_t)(tb0 + c)*NWV + q*8 + seg*2;
      #pragma unroll
      for (int half = 0; half < 2; ++half) {
        u64 mm = vp[half];
        int kbase = seg*128 + half*64;
        #pragma unroll
        for (int j2 = 0; j2 < 32; ++j2) {
          int k = kbase + 2*j2;
          u32 val = (u32)((mm >> (2*j2)) & 1ull) * 0x3F80u
                  | (u32)((mm >> (2*j2+1)) & 1ull) * 0x3F800000u;
          int blk = (k >> 3) ^ (c & 7);
          *(u32*)&Blds[c*BSTh + (blk << 3) + (k & 7)] = val;
        }
      }
    }
    __syncthreads();
    for (int ks = 0; ks < 16; ++ks) {
      int kt = q*16 + ks;
      bf16x8 bf[2];
      #pragma unroll
      for (int n = 0; n < 2; ++n) {
        int col = wc*32 + n*16 + (l & 15);
        int k = ks*32 + ((l >> 4) << 3);
        int blk = (k >> 3) ^ (col & 7);
        bf[n] = *(const bf16x8*)&Blds[col*BSTh + (blk << 3)];
      }
      #pragma unroll
      for (int m = 0; m < 2; ++m) {
        int ht = hblk*4 + wr*2 + m;
        size_t abase = (((size_t)ht*32 + kt)*64 + l)*8;
        bf16x8 a1 = *(const bf16x8*)&AW1[abase];
        bf16x8 a2 = *(const bf16x8*)&AW2[abase];
        #pragma unroll
        for (int n = 0; n < 2; ++n) {
          acc[m][n] = __builtin_amdgcn_mfma_f32_16x16x32_bf16(a1, bf[n], acc[m][n], 0,0,0);
          acc[m][n] = __builtin_amdgcn_mfma_f32_16x16x32_bf16(a2, bf[n], acc[m][n], 0,0,0);
        }
      }
    }
    __syncthreads();
  }

  // ---- R phases (U @ r_lag), bf16 planes pl=0,1; coalesced staging
  if (t > 0) {
    int tbl0 = tb0 - 256;
    for (int pl = 0; pl < 2; ++pl) {
      {
        int c  = tid & 63;
        int q4 = tid >> 6;                     // 0..3
        const float* __restrict__ rp = r32 + tbl0 + c;
        for (int rr = 0; rr < 128; ++rr) {
          int r = q4*128 + rr;
          float x = rp[(size_t)r*TBsz];
          __hip_bfloat16 b1 = __float2bfloat16(x);
          ushort ub;
          if (pl == 0) {
            ub = *reinterpret_cast<ushort*>(&b1);
          } else {
            float res = x - __bfloat162float(b1);
            __hip_bfloat16 b2 = __float2bfloat16(res);
            ub = *reinterpret_cast<ushort*>(&b2);
          }
          int blk = (r >> 3) ^ (c & 7);
          Blds[c*BSTh + (blk << 3) + (r & 7)] = ub;
        }
      }
      __syncthreads();
      for (int ks = 0; ks < 16; ++ks) {
        bf16x8 bf[2];
        #pragma unroll
        for (int n = 0; n < 2; ++n) {
          int col = wc*32 + n*16 + (l & 15);
          int k = ks*32 + ((l >> 4) << 3);
          int blk = (k >> 3) ^ (col & 7);
          bf[n] = *(const bf16x8*)&Blds[col*BSTh + (blk << 3)];
        }
        #pragma unroll
        for (int m = 0; m < 2; ++m) {
          int ht = hblk*4 + wr*2 + m;
          size_t abase = (((size_t)ht*16 + ks)*64 + l)*8;
          bf16x8 a1 = *(const bf16x8*)&AU1[abase];
          bf16x8 a2 = *(const bf16x8*)&AU2[abase];
          #pragma unroll
          for (int n = 0; n < 2; ++n) {
            acc[m][n] = __builtin_amdgcn_mfma_f32_16x16x32_bf16(a1, bf[n], acc[m][n], 0,0,0);
            acc[m][n] = __builtin_amdgcn_mfma_f32_16x16x32_bf16(a2, bf[n], acc[m][n], 0,0,0);
          }
        }
      }
      __syncthreads();
    }
  }

  // ---- epilogue: sigmoid + threefry bernoulli + queue + bit-pack
  const float* __restrict__ bias = (t > 0) ? bh : binit;
  u64 mask[2] = {0, 0};
  int coln[2];
  #pragma unroll
  for (int n = 0; n < 2; ++n) {
    int col = wc*32 + n*16 + (l & 15);
    coln[n] = col;
    int tb = tb0 + col;
    #pragma unroll
    for (int m = 0; m < 2; ++m) {
      #pragma unroll
      for (int r = 0; r < 4; ++r) {
        int hrel = wr*32 + m*16 + ((l >> 4) << 2) + r;
        int h = h0 + hrel;
        float p = 1.f / (1.f + __expf(-(acc[m][n][r] + bias[h])));
        size_t o = (size_t)h*TBsz + tb;
        double u = tf_uniform64(k0, k1, (u32)o);
        double diff = (double)p - u;
        unsigned smp = diff > 0.0 ? 1u : 0u;
        if (fabs(diff) < DELTA) {
          u32 s = atomicAdd(cnt, 1u);
          if (s < QCAP) queue[s] = (u32)o;
        }
        if (smp) mask[n] |= 1ull << hrel;
      }
    }
  }
  __syncthreads();
  u64* sbits = (u64*)Blds;
  if (tid < 64) sbits[tid] = 0;
  __syncthreads();
  atomicOr(&sbits[coln[0]], mask[0]);
  atomicOr(&sbits[coln[1]], mask[1]);
  __syncthreads();
  if (tid < 64)
    h2bits[(size_t)(tb0 + tid)*NWH + hblk] = sbits[tid];
}

// ---------------- v-side exact fixup (f64) --------------------------------------
__global__ __launch_bounds__(256) void kvis_fix(
    const float* __restrict__ W, const float* __restrict__ bv,
    const u64* __restrict__ hbits, u64* __restrict__ fixbits,
    float* __restrict__ vf, const u32* __restrict__ queue,
    const u32* __restrict__ cnt, u32 k0, u32 k1) {
  u32 n = *cnt; if (n > QCAP) n = QCAP;
  for (u32 q = blockIdx.x*256 + threadIdx.x; q < n; q += gridDim.x*256) {
    u32 o = queue[q];
    u32 v = o / TBsz, tb = o % TBsz;
    double a0=0, a1=0, a2=0, a3=0;
    for (int w = 0; w < NWH; ++w) {
      u64 mw = hbits[(size_t)tb*NWH + w];
      for (int j = 0; j < 64; j += 4) {
        if ((mw >> (j+0)) & 1ull) a0 += (double)W[(size_t)(w*64+j+0)*NV + v];
        if ((mw >> (j+1)) & 1ull) a1 += (double)W[(size_t)(w*64+j+1)*NV + v];
        if ((mw >> (j+2)) & 1ull) a2 += (double)W[(size_t)(w*64+j+2)*NV + v];
        if ((mw >> (j+3)) & 1ull) a3 += (double)W[(size_t)(w*64+j+3)*NV + v];
      }
    }
    double p = sigmoid64(((a0+a1)+(a2+a3)) + (double)bv[v]);
    double u = tf_uniform64(k0, k1, o);
    unsigned smp = (u < p) ? 1u : 0u;
    if (vf) vf[o] = (float)smp;
    if (fixbits) {
      size_t wi = (size_t)tb*NWV + (v >> 6);
      unsigned bit = v & 63u;
      unsigned cur = (unsigned)((fixbits[wi] >> bit) & 1ull);
      if (cur != smp) atomicXor(&fixbits[wi], 1ull << bit);
    }
  }
}

// ---------------- h-side exact fixup (f64) --------------------------------------
__global__ __launch_bounds__(256) void khid_fix(
    const u64* __restrict__ vbits, const float* __restrict__ W,
    const double* __restrict__ U64, const float* __restrict__ bh,
    const float* __restrict__ binit, const double* __restrict__ rT,
    u64* __restrict__ fixbits, const u32* __restrict__ queue,
    const u32* __restrict__ cnt, u32 k0, u32 k1) {
  u32 n = *cnt; if (n > QCAP) n = QCAP;
  for (u32 q = blockIdx.x*256 + threadIdx.x; q < n; q += gridDim.x*256) {
    u32 o = queue[q];
    u32 h = o / TBsz, tb = o % TBsz;
    u32 t = tb / BB, b = tb % BB;
    double a0=0, a1=0, a2=0, a3=0;
    for (int w = 0; w < NWV; ++w) {
      u64 mw = vbits[(size_t)tb*NWV + w];
      for (int j = 0; j < 64; j += 4) {
        if ((mw >> (j+0)) & 1ull) a0 += (double)W[(size_t)h*NV + w*64+j+0];
        if ((mw >> (j+1)) & 1ull) a1 += (double)W[(size_t)h*NV + w*64+j+1];
        if ((mw >> (j+2)) & 1ull) a2 += (double)W[(size_t)h*NV + w*64+j+2];
        if ((mw >> (j+3)) & 1ull) a3 += (double)W[(size_t)h*NV + w*64+j+3];
      }
    }
    double logit = (a0+a1) + (a2+a3);
    if (t > 0) {
      const double* __restrict__ rp = rT + ((size_t)(t-1)*BB + b)*NH;
      const double* __restrict__ Ur = U64 + (size_t)h*NH;
      double u0=0, u1=0, u2=0, u3=0;
      for (int r = 0; r < NH; r += 4) {
        u0 = fma(Ur[r+0], rp[r+0], u0);
        u1 = fma(Ur[r+1], rp[r+1], u1);
        u2 = fma(Ur[r+2], rp[r+2], u2);
        u3 = fma(Ur[r+3], rp[r+3], u3);
      }
      logit = (logit + ((u0+u1)+(u2+u3))) + (double)bh[h];
    } else {
      logit += (double)binit[h];
    }
    double p = sigmoid64(logit);
    double u = tf_uniform64(k0, k1, o);
    unsigned smp = (u < p) ? 1u : 0u;
    size_t wi = (size_t)tb*NWH + (h >> 6);
    unsigned bit = h & 63u;
    unsigned cur = (unsigned)((fixbits[wi] >> bit) & 1ull);
    if (cur != smp) atomicXor(&fixbits[wi], 1ull << bit);
  }
}

extern "C" void kernel_launch(void* const* d_in, const int* in_sizes, int n_in,
                              void* d_out, int out_size, void* d_ws, size_t ws_size,
                              hipStream_t stream) {
  const float* vd    = (const float*)d_in[0];
  const float* W     = (const float*)d_in[1];
  const float* U     = (const float*)d_in[2];
  const float* bh    = (const float*)d_in[3];
  const float* binit = (const float*)d_in[4];
  const float* bv    = (const float*)d_in[5];

  float* out_v = (float*)d_out;            // (V,T,B) final samples (written last)
  float* out_r = (float*)d_out + VTBsz;    // (H,T,B) r_data f32
  double* WvT = (double*)d_out;            // aliases out_v region; dead by final kvisM

  // ws layout (~171 MB)
  char* w = (char*)d_ws;
  double* rT    = (double*)w;  w += (size_t)HTBsz*8;        // 134.2 MB, [t][b][h]
  u64* vdbits   = (u64*)w;     w += (size_t)TBsz*NWV*8;     // 4 MB
  u64* v1bits   = (u64*)w;     w += (size_t)TBsz*NWV*8;     // 4 MB
  u64* h1bits   = (u64*)w;     w += (size_t)TBsz*NWH*8;     // 2 MB
  u64* h2bits   = (u64*)w;     w += (size_t)TBsz*NWH*8;     // 2 MB
  double* W64   = (double*)w;  w += (size_t)NH*NV*8;        // 4 MB
  double* U64   = (double*)w;  w += (size_t)NH*NH*8;        // 2 MB
  float4* UB    = (float4*)w;  w += (size_t)NH*NH*4;        // 1 MB
  ushort* A1    = (ushort*)w;  w += (size_t)NH*NV*2;        // 1 MB
  ushort* A2    = (ushort*)w;  w += (size_t)NH*NV*2;        // 1 MB
  ushort* AW1   = (ushort*)w;  w += (size_t)NH*NV*2;        // 1 MB
  ushort* AW2   = (ushort*)w;  w += (size_t)NH*NV*2;        // 1 MB
  ushort* AU1   = (ushort*)w;  w += (size_t)NH*NH*2;        // 0.5 MB
  ushort* AU2   = (ushort*)w;  w += (size_t)NH*NH*2;        // 0.5 MB
  u32* q0       = (u32*)w;     w += (size_t)QCAP*4;         // 4 MB
  u32* q1       = (u32*)w;     w += (size_t)QCAP*4;         // 4 MB
  u32* q2       = (u32*)w;     w += (size_t)QCAP*4;         // 4 MB
  u32* cnt      = (u32*)w;     w += 256;
  (void)ws_size; (void)in_sizes; (void)n_in; (void)out_size;

  // host-side key derivation (jax.random.key(42), partitionable threefry splits)
  uint32_t ka0,ka1, sk0,sk1;
  tf2x32(0u,42u, 0u,0u, ka0,ka1);
  tf2x32(0u,42u, 0u,1u, sk0,sk1);
  uint32_t kb0,kb1, k10,k11, k20,k21;
  tf2x32(ka0,ka1, 0u,0u, kb0,kb1);
  tf2x32(ka0,ka1, 0u,1u, k10,k11);
  tf2x32(ka0,ka1, 0u,2u, k20,k21);
  uint32_t kc0,kc1, kf0,kf1;
  tf2x32(kb0,kb1, 0u,0u, kc0,kc1);
  tf2x32(kb0,kb1, 0u,1u, kf0,kf1);

  hipMemsetAsync(cnt, 0, 3*sizeof(u32), stream);

  // 0) fused preps
  kprepWall<<<(NH*NV)/256, 256, 0, stream>>>(W, W64, A1, A2, AW1, AW2);
  kprepUall<<<(NH*NH)/256, 256, 0, stream>>>(U, U64, UB, AU1, AU2);
  kpack_f32<<<2048, 256, 0, stream>>>(vd, vdbits);

  // 1) WvT = (W @ v_data)^T  (f64, broadcast-W, TBM=2)
  kWv<<<(TT/2)*(NH/8), 256, 0, stream>>>(vdbits, W64, WvT);

  // 2) fused mean-field recurrence (R8-proven structure)
  krecur<<<BB, NH, 0, stream>>>(WvT, UB, bh, binit, rT);

  // 2b) out_r transpose + h1 = bernoulli(sk, r) fused
  ktrans_s<<<dim3(TT, NH/32, BB/32), 256, 0, stream>>>(rT, out_r,
                                                       (uint8_t*)h1bits, sk0, sk1);

  // 3) v1 = bernoulli(k1, sigmoid(W^T h1 + bv)) : bf16-MFMA fast + f64 fix
  kvisM<<<TBsz/128, 256, 0, stream>>>(A1, A2, bv, h1bits, v1bits, nullptr,
                                      q0, cnt+0, k10, k11);
  kvis_fix<<<256, 256, 0, stream>>>(W, bv, h1bits, v1bits, nullptr,
                                    q0, cnt+0, k10, k11);

  // 4) h2 = bernoulli(k2, sigmoid(W v1 + U r_lag + bias)) : bf16-MFMA + f64 fix
  khidM<<<8*512, 256, 0, stream>>>(AW1, AW2, AU1, AU2, bh, binit,
                                   v1bits, out_r, h2bits, q1, cnt+1, k20, k21);
  khid_fix<<<256, 256, 0, stream>>>(v1bits, W, U64, bh, binit, rT,
                                    h2bits, q1, cnt+1, k20, k21);

  // 5) v_model = bernoulli(kf, sigmoid(W^T h2 + bv)) -> out_v
  kvisM<<<TBsz/128, 256, 0, stream>>>(A1, A2, bv, h2bits, nullptr, out_v,
                                      q2, cnt+2, kf0, kf1);
  kvis_fix<<<256, 256, 0, stream>>>(W, bv, h2bits, nullptr, out_v,
                                    q2, cnt+2, kf0, kf1);
}

// Round 16
// 4857.003 us; speedup vs baseline: 1.0812x; 1.0812x over previous
//
#include <hip/hip_runtime.h>
#include <hip/hip_bf16.h>
#include <stdint.h>

typedef unsigned long long u64;
typedef uint32_t u32;
typedef __attribute__((ext_vector_type(8))) short bf16x8;
typedef __attribute__((ext_vector_type(4))) float f32x4;

// RTRBM CD-k step. Exact JAX-threefry; f64 where sample margins demand it;
// bf16-pair MFMA fast paths + f64 boundary fixups for all sampling GEMMs.
// (R14-proven configuration: kWv broadcast-W, bank-padded MFMA staging.)
#define NV 1024
#define NH 512
#define TT 128
#define BB 256
#define TBsz (TT*BB)          // 32768
#define HTBsz (NH*TBsz)       // 16777216
#define VTBsz (NV*TBsz)       // 33554432
#define NWV (NV/64)           // 16
#define NWH (NH/64)           // 8
#define QCAP 1048576u
#define DELTA 5e-4
#define BSTv 528              // kvisM LDS col stride (ushorts), bank-padded
#define BSTh 528              // khidM LDS col stride

// ---------------- Threefry-2x32 (JAX exact) ----------------
__host__ __device__ inline void tf2x32(uint32_t k0, uint32_t k1,
                                       uint32_t x0, uint32_t x1,
                                       uint32_t& o0, uint32_t& o1) {
  const uint32_t ks2 = k0 ^ k1 ^ 0x1BD11BDAu;
#define ROTL(x,d) (((x)<<(d))|((x)>>(32-(d))))
#define RND(r) { x0 += x1; x1 = ROTL(x1,r); x1 ^= x0; }
  x0 += k0;  x1 += k1;
  RND(13) RND(15) RND(26) RND(6)
  x0 += k1;  x1 += ks2 + 1u;
  RND(17) RND(29) RND(16) RND(24)
  x0 += ks2; x1 += k0 + 2u;
  RND(13) RND(15) RND(26) RND(6)
  x0 += k0;  x1 += k1 + 3u;
  RND(17) RND(29) RND(16) RND(24)
  x0 += k1;  x1 += ks2 + 4u;
  RND(13) RND(15) RND(26) RND(6)
  x0 += ks2; x1 += k0 + 5u;
  o0 = x0; o1 = x1;
#undef RND
#undef ROTL
}

__device__ inline double tf_uniform64(uint32_t k0, uint32_t k1, uint32_t i) {
  uint32_t o0, o1;
  tf2x32(k0, k1, 0u, i, o0, o1);
  uint32_t bits = o0 ^ o1;
  uint32_t fb = (bits >> 9) | 0x3f800000u;
  float f = __uint_as_float(fb) - 1.0f;
  return (double)f;
}

__device__ inline double sigmoid64(double x) { return 1.0 / (1.0 + exp(-x)); }

__device__ inline void bfsplit(float w, ushort& b1o, ushort& b2o) {
  __hip_bfloat16 b1 = __float2bfloat16(w);
  float r = w - __bfloat162float(b1);
  __hip_bfloat16 b2 = __float2bfloat16(r);
  b1o = *reinterpret_cast<ushort*>(&b1);
  b2o = *reinterpret_cast<ushort*>(&b2);
}

// ------- fused W preps: W64 (f64 copy) + kvisM frags + khidM frags --------------
__global__ __launch_bounds__(256) void kprepWall(const float* __restrict__ W,
                                                 double* __restrict__ W64,
                                                 ushort* __restrict__ A1,
                                                 ushort* __restrict__ A2,
                                                 ushort* __restrict__ AW1,
                                                 ushort* __restrict__ AW2) {
  int idx = blockIdx.x * 256 + threadIdx.x;     // 524288
  W64[idx] = (double)W[idx];
  {  // kvisM: W^T fragments (row=v, k=h)
    int i    = idx & 7;
    int lane = (idx >> 3) & 63;
    int ks   = (idx >> 9) & 15;
    int vt   = idx >> 13;
    int h = ks*32 + ((lane >> 4) << 3) + i;
    int v = vt*16 + (lane & 15);
    bfsplit(W[(size_t)h*NV + v], A1[idx], A2[idx]);
  }
  {  // khidM: W fragments (row=h, k=v)
    int i    = idx & 7;
    int lane = (idx >> 3) & 63;
    int kt   = (idx >> 9) & 31;
    int ht   = idx >> 14;
    int h = ht*16 + (lane & 15);
    int v = kt*32 + ((lane >> 4) << 3) + i;
    bfsplit(W[(size_t)h*NV + v], AW1[idx], AW2[idx]);
  }
}

// ------- fused U preps: U64 + UB (blocked) + khidM AU frags ---------------------
__global__ __launch_bounds__(256) void kprepUall(const float* __restrict__ U,
                                                 double* __restrict__ U64,
                                                 float4* __restrict__ UB,
                                                 ushort* __restrict__ AU1,
                                                 ushort* __restrict__ AU2) {
  int idx = blockIdx.x * 256 + threadIdx.x;     // 262144
  U64[idx] = (double)U[idx];
  {  // AU fragments (row=h, k=r)
    int i    = idx & 7;
    int lane = (idx >> 3) & 63;
    int kt   = (idx >> 9) & 15;
    int ht   = idx >> 13;
    int h = ht*16 + (lane & 15);
    int r = kt*32 + ((lane >> 4) << 3) + i;
    bfsplit(U[(size_t)h*NH + r], AU1[idx], AU2[idx]);
  }
  if (idx < NH*NH/4) {  // UB[r4*NH + h]
    int r4 = idx / NH;
    int h  = idx % NH;
    const float* __restrict__ p = U + (size_t)h*NH + r4*4;
    UB[idx] = make_float4(p[0], p[1], p[2], p[3]);
  }
}

// ---------------- bit-pack v_data: f32 [NV][TBsz] -> u64 [TBsz][NWV] -----------
__global__ __launch_bounds__(256) void kpack_f32(const float* __restrict__ in,
                                                 u64* __restrict__ out) {
  int bw = blockIdx.x >> 7;                    // 0..15
  int tb = (blockIdx.x & 127) * 256 + threadIdx.x;
  u64 m = 0;
  #pragma unroll 8
  for (int j = 0; j < 64; ++j)
    m |= (u64)(in[(size_t)(bw*64 + j)*TBsz + tb] != 0.0f ? 1 : 0) << j;
  out[(size_t)tb*NWV + bw] = m;
}

// ------- WvT[(t*BB+b)*NH + h] = sum_v W[h,v]*vbit  (f64, broadcast W — R12) ----
__global__ __launch_bounds__(256) void kWv(const u64* __restrict__ vb,
                                           const double* __restrict__ W64,
                                           double* __restrict__ WvT) {
  const int HM = 8;
  int t  = blockIdx.x / (NH/HM);
  int h0 = (blockIdx.x % (NH/HM)) * HM;
  int tb = t*BB + threadIdx.x;
  u64 m[NWV];
  #pragma unroll
  for (int w = 0; w < NWV; ++w) m[w] = vb[(size_t)tb*NWV + w];
  double acc[HM];
  #pragma unroll
  for (int i = 0; i < HM; ++i) acc[i] = 0.0;
  const double2* __restrict__ W2 = (const double2*)W64;
  for (int w = 0; w < NWV; ++w) {
    u64 mw = m[w];
    #pragma unroll 8
    for (int j2 = 0; j2 < 32; ++j2) {
      double bd0 = (double)((unsigned)((mw >> (2*j2+0)) & 1ull));
      double bd1 = (double)((unsigned)((mw >> (2*j2+1)) & 1ull));
      int vi = w*32 + j2;
      #pragma unroll
      for (int i = 0; i < HM; ++i) {
        double2 wv = W2[(size_t)(h0+i)*(NV/2) + vi];
        acc[i] = fma(bd0, wv.x, acc[i]);
        acc[i] = fma(bd1, wv.y, acc[i]);
      }
    }
  }
  #pragma unroll
  for (int i = 0; i < HM; ++i)
    WvT[(size_t)tb*NH + h0 + i] = acc[i];
}

// ---------------- fused recurrence (R8-proven): 256 blocks x 512 thr ------------
__global__ __launch_bounds__(512) void krecur(const double* __restrict__ WvT,
                                              const float4* __restrict__ UB,
                                              const float* __restrict__ bh,
                                              const float* __restrict__ binit,
                                              double* __restrict__ rT) {
  __shared__ double rA[2][NH];
  const int b = blockIdx.x;
  const int h = threadIdx.x;
  const double bhd = (double)bh[h];
  double p = sigmoid64(WvT[(size_t)b*NH + h] + (double)binit[h]);
  rA[0][h] = p;
  rT[(size_t)b*NH + h] = p;
  __syncthreads();
  int cur = 0;
  for (int t = 1; t < TT; ++t) {
    double acc = WvT[((size_t)t*BB + b)*NH + h];
    double a0=0, a1=0, a2=0, a3=0;
    const double2* __restrict__ rA2 = (const double2*)rA[cur];
    #pragma unroll 4
    for (int r = 0; r < NH; r += 4) {
      float4 u4 = UB[(size_t)(r >> 2)*NH + h];
      double2 q01 = rA2[(r>>1)+0];
      double2 q23 = rA2[(r>>1)+1];
      a0 = fma((double)u4.x, q01.x, a0);
      a1 = fma((double)u4.y, q01.y, a1);
      a2 = fma((double)u4.z, q23.x, a2);
      a3 = fma((double)u4.w, q23.y, a3);
    }
    p = sigmoid64((acc + ((a0+a1)+(a2+a3))) + bhd);
    rA[cur ^ 1][h] = p;
    rT[((size_t)t*BB + b)*NH + h] = p;
    __syncthreads();
    cur ^= 1;
  }
}

// ------ transpose rT -> out_r f32, fused h1 = bernoulli(sk, r) ------------------
__global__ __launch_bounds__(256) void ktrans_s(const double* __restrict__ rT,
                                                float* __restrict__ out_r,
                                                uint8_t* __restrict__ hbytes,
                                                u32 k0, u32 k1) {
  __shared__ double lds[32][33];
  int t  = blockIdx.x;
  int h0 = blockIdx.y * 32;
  int b0 = blockIdx.z * 32;
  int tx = threadIdx.x & 31;
  int ty = threadIdx.x >> 5;
  #pragma unroll
  for (int i = 0; i < 4; ++i) {
    int row = ty*4 + i;
    lds[row][tx] = rT[((size_t)t*BB + b0 + row)*NH + h0 + tx];
  }
  __syncthreads();
  #pragma unroll
  for (int i = 0; i < 4; ++i) {
    int row = ty*4 + i;
    out_r[(size_t)(h0+row)*TBsz + (size_t)t*BB + b0 + tx] = (float)lds[tx][row];
  }
  if (threadIdx.x < 128) {
    int tbr = threadIdx.x >> 2;
    int bix = threadIdx.x & 3;
    int tb  = t*BB + b0 + tbr;
    unsigned byte = 0;
    #pragma unroll
    for (int j = 0; j < 8; ++j) {
      int hrel = bix*8 + j;
      double p = lds[tbr][hrel];
      double u = tf_uniform64(k0, k1, (u32)((h0 + hrel)*TBsz + tb));
      byte |= (u < p) ? (1u << j) : 0u;
    }
    hbytes[(size_t)tb*(NH/8) + (h0 >> 3) + bix] = (uint8_t)byte;
  }
}

// -------- v-side MFMA, stage-once: grid 256 (tb-tiles of 128), loop 16 vblk -----
__global__ __launch_bounds__(256) void kvisM(
    const ushort* __restrict__ A1, const ushort* __restrict__ A2,
    const float* __restrict__ bv, const u64* __restrict__ hbits,
    u64* __restrict__ vbits, float* __restrict__ vf,
    u32* __restrict__ queue, u32* __restrict__ cnt, u32 k0, u32 k1) {
  __shared__ ushort Blds[128*BSTv];            // 132 KB (bank-padded stride)
  __shared__ u64 sbits[128];
  int tb0 = blockIdx.x * 128;
  int tid = threadIdx.x;
  // stage B once: col c, half hs; bits -> bf16 0/1, k-block XOR-swizzled
  {
    int c  = tid & 127;
    int hs = tid >> 7;                         // 0..1
    const u64* hp = hbits + (size_t)(tb0 + c)*NWH + hs*4;
    #pragma unroll
    for (int w = 0; w < 4; ++w) {
      u64 mm = hp[w];
      int kbase = hs*256 + w*64;
      #pragma unroll
      for (int j2 = 0; j2 < 32; ++j2) {
        int k = kbase + 2*j2;
        u32 val = (u32)((mm >> (2*j2)) & 1ull) * 0x3F80u
                | (u32)((mm >> (2*j2+1)) & 1ull) * 0x3F800000u;
        int blk = (k >> 3) ^ (c & 7);
        *(u32*)&Blds[c*BSTv + (blk << 3) + (k & 7)] = val;
      }
    }
  }
  __syncthreads();
  int wv = tid >> 6, l = tid & 63;
  int wr = wv >> 1, wc = wv & 1;
  for (int vblk = 0; vblk < 16; ++vblk) {
    f32x4 acc[2][4];
    #pragma unroll
    for (int m = 0; m < 2; ++m)
      #pragma unroll
      for (int n = 0; n < 4; ++n) acc[m][n] = (f32x4){0.f,0.f,0.f,0.f};
    for (int ks = 0; ks < 16; ++ks) {
      bf16x8 bf[4];
      #pragma unroll
      for (int n = 0; n < 4; ++n) {
        int col = wc*64 + n*16 + (l & 15);
        int k = ks*32 + ((l >> 4) << 3);
        int blk = (k >> 3) ^ (col & 7);
        bf[n] = *(const bf16x8*)&Blds[col*BSTv + (blk << 3)];
      }
      #pragma unroll
      for (int m = 0; m < 2; ++m) {
        int vt = vblk*4 + wr*2 + m;
        size_t abase = (((size_t)vt*16 + ks)*64 + l)*8;
        bf16x8 a1 = *(const bf16x8*)&A1[abase];
        bf16x8 a2 = *(const bf16x8*)&A2[abase];
        #pragma unroll
        for (int n = 0; n < 4; ++n) {
          acc[m][n] = __builtin_amdgcn_mfma_f32_16x16x32_bf16(a1, bf[n], acc[m][n], 0,0,0);
          acc[m][n] = __builtin_amdgcn_mfma_f32_16x16x32_bf16(a2, bf[n], acc[m][n], 0,0,0);
        }
      }
    }
    int v0 = vblk * 64;
    u64 mask[4] = {0,0,0,0};
    #pragma unroll
    for (int n = 0; n < 4; ++n) {
      int col = wc*64 + n*16 + (l & 15);
      int tb = tb0 + col;
      #pragma unroll
      for (int m = 0; m < 2; ++m) {
        #pragma unroll
        for (int r = 0; r < 4; ++r) {
          int vrel = wr*32 + m*16 + ((l >> 4) << 2) + r;
          int v = v0 + vrel;
          float p = 1.f / (1.f + __expf(-(acc[m][n][r] + bv[v])));
          size_t o = (size_t)v*TBsz + tb;
          double u = tf_uniform64(k0, k1, (u32)o);
          double diff = (double)p - u;
          unsigned smp = diff > 0.0 ? 1u : 0u;
          if (fabs(diff) < DELTA) {
            u32 s = atomicAdd(cnt, 1u);
            if (s < QCAP) queue[s] = (u32)o;
          }
          if (smp) mask[n] |= 1ull << vrel;
          if (vf) vf[o] = (float)smp;
        }
      }
    }
    if (vbits) {
      __syncthreads();
      if (tid < 128) sbits[tid] = 0;
      __syncthreads();
      #pragma unroll
      for (int n = 0; n < 4; ++n) {
        int col = wc*64 + n*16 + (l & 15);
        atomicOr(&sbits[col], mask[n]);
      }
      __syncthreads();
      if (tid < 128)
        vbits[(size_t)(tb0 + tid)*NWV + vblk] = sbits[tid];
    }
  }
}

// ---------------- h-side MFMA: O[h][tb] = W@v1 + U@r_lag ------------------------
__global__ __launch_bounds__(256) void khidM(
    const ushort* __restrict__ AW1, const ushort* __restrict__ AW2,
    const ushort* __restrict__ AU1, const ushort* __restrict__ AU2,
    const float* __restrict__ bh, const float* __restrict__ binit,
    const u64* __restrict__ vbits, const float* __restrict__ r32,
    u64* __restrict__ h2bits, u32* __restrict__ queue,
    u32* __restrict__ cnt, u32 k0, u32 k1) {
  __shared__ ushort Blds[64*BSTh];             // 66 KB
  int nblk = blockIdx.x & 511;
  int hblk = blockIdx.x >> 9;                  // 0..7
  int tb0 = nblk * 64, h0 = hblk * 64;
  int t = tb0 >> 8;
  int tid = threadIdx.x;
  int wv = tid >> 6, l = tid & 63;
  int wr = wv >> 1, wc = wv & 1;
  f32x4 acc[2][2];
  #pragma unroll
  for (int m = 0; m < 2; ++m)
    #pragma unroll
    for (int n = 0; n < 2; ++n) acc[m][n] = (f32x4){0.f,0.f,0.f,0.f};

  // ---- V phases (W @ v1bits), K chunks q=0,1
  for (int q = 0; q < 2; ++q) {
    {
      int c = tid >> 2, seg = tid & 3;
      const u64* vp = vbits + (size_t)(tb0 + c)*NWV + q*8 + seg*2;
      #pragma unroll
      for (int half = 0; half < 2; ++half) {
        u64 mm = vp[half];
        int kbase = seg*128 + half*64;
        #pragma unroll
        for (int j2 = 0; j2 < 32; ++j2) {
          int k = kbase + 2*j2;
          u32 val = (u32)((mm >> (2*j2)) & 1ull) * 0x3F80u
                  | (u32)((mm >> (2*j2+1)) & 1ull) * 0x3F800000u;
          int blk = (k >> 3) ^ (c & 7);
          *(u32*)&Blds[c*BSTh + (blk << 3) + (k & 7)] = val;
        }
      }
    }
    __syncthreads();
    for (int ks = 0; ks < 16; ++ks) {
      int kt = q*16 + ks;
      bf16x8 bf[2];
      #pragma unroll
      for (int n = 0; n < 2; ++n) {
        int col = wc*32 + n*16 + (l & 15);
        int k = ks*32 + ((l >> 4) << 3);
        int blk = (k >> 3) ^ (col & 7);
        bf[n] = *(const bf16x8*)&Blds[col*BSTh + (blk << 3)];
      }
      #pragma unroll
      for (int m = 0; m < 2; ++m) {
        int ht = hblk*4 + wr*2 + m;
        size_t abase = (((size_t)ht*32 + kt)*64 + l)*8;
        bf16x8 a1 = *(const bf16x8*)&AW1[abase];
        bf16x8 a2 = *(const bf16x8*)&AW2[abase];
        #pragma unroll
        for (int n = 0; n < 2; ++n) {
          acc[m][n] = __builtin_amdgcn_mfma_f32_16x16x32_bf16(a1, bf[n], acc[m][n], 0,0,0);
          acc[m][n] = __builtin_amdgcn_mfma_f32_16x16x32_bf16(a2, bf[n], acc[m][n], 0,0,0);
        }
      }
    }
    __syncthreads();
  }

  // ---- R phases (U @ r_lag), bf16 planes pl=0,1; coalesced staging
  if (t > 0) {
    int tbl0 = tb0 - 256;
    for (int pl = 0; pl < 2; ++pl) {
      {
        int c  = tid & 63;
        int q4 = tid >> 6;                     // 0..3
        const float* __restrict__ rp = r32 + tbl0 + c;
        for (int rr = 0; rr < 128; ++rr) {
          int r = q4*128 + rr;
          float x = rp[(size_t)r*TBsz];
          __hip_bfloat16 b1 = __float2bfloat16(x);
          ushort ub;
          if (pl == 0) {
            ub = *reinterpret_cast<ushort*>(&b1);
          } else {
            float res = x - __bfloat162float(b1);
            __hip_bfloat16 b2 = __float2bfloat16(res);
            ub = *reinterpret_cast<ushort*>(&b2);
          }
          int blk = (r >> 3) ^ (c & 7);
          Blds[c*BSTh + (blk << 3) + (r & 7)] = ub;
        }
      }
      __syncthreads();
      for (int ks = 0; ks < 16; ++ks) {
        bf16x8 bf[2];
        #pragma unroll
        for (int n = 0; n < 2; ++n) {
          int col = wc*32 + n*16 + (l & 15);
          int k = ks*32 + ((l >> 4) << 3);
          int blk = (k >> 3) ^ (col & 7);
          bf[n] = *(const bf16x8*)&Blds[col*BSTh + (blk << 3)];
        }
        #pragma unroll
        for (int m = 0; m < 2; ++m) {
          int ht = hblk*4 + wr*2 + m;
          size_t abase = (((size_t)ht*16 + ks)*64 + l)*8;
          bf16x8 a1 = *(const bf16x8*)&AU1[abase];
          bf16x8 a2 = *(const bf16x8*)&AU2[abase];
          #pragma unroll
          for (int n = 0; n < 2; ++n) {
            acc[m][n] = __builtin_amdgcn_mfma_f32_16x16x32_bf16(a1, bf[n], acc[m][n], 0,0,0);
            acc[m][n] = __builtin_amdgcn_mfma_f32_16x16x32_bf16(a2, bf[n], acc[m][n], 0,0,0);
          }
        }
      }
      __syncthreads();
    }
  }

  // ---- epilogue: sigmoid + threefry bernoulli + queue + bit-pack
  const float* __restrict__ bias = (t > 0) ? bh : binit;
  u64 mask[2] = {0, 0};
  int coln[2];
  #pragma unroll
  for (int n = 0; n < 2; ++n) {
    int col = wc*32 + n*16 + (l & 15);
    coln[n] = col;
    int tb = tb0 + col;
    #pragma unroll
    for (int m = 0; m < 2; ++m) {
      #pragma unroll
      for (int r = 0; r < 4; ++r) {
        int hrel = wr*32 + m*16 + ((l >> 4) << 2) + r;
        int h = h0 + hrel;
        float p = 1.f / (1.f + __expf(-(acc[m][n][r] + bias[h])));
        size_t o = (size_t)h*TBsz + tb;
        double u = tf_uniform64(k0, k1, (u32)o);
        double diff = (double)p - u;
        unsigned smp = diff > 0.0 ? 1u : 0u;
        if (fabs(diff) < DELTA) {
          u32 s = atomicAdd(cnt, 1u);
          if (s < QCAP) queue[s] = (u32)o;
        }
        if (smp) mask[n] |= 1ull << hrel;
      }
    }
  }
  __syncthreads();
  u64* sbits = (u64*)Blds;
  if (tid < 64) sbits[tid] = 0;
  __syncthreads();
  atomicOr(&sbits[coln[0]], mask[0]);
  atomicOr(&sbits[coln[1]], mask[1]);
  __syncthreads();
  if (tid < 64)
    h2bits[(size_t)(tb0 + tid)*NWH + hblk] = sbits[tid];
}

// ---------------- v-side exact fixup (f64) --------------------------------------
__global__ __launch_bounds__(256) void kvis_fix(
    const float* __restrict__ W, const float* __restrict__ bv,
    const u64* __restrict__ hbits, u64* __restrict__ fixbits,
    float* __restrict__ vf, const u32* __restrict__ queue,
    const u32* __restrict__ cnt, u32 k0, u32 k1) {
  u32 n = *cnt; if (n > QCAP) n = QCAP;
  for (u32 q = blockIdx.x*256 + threadIdx.x; q < n; q += gridDim.x*256) {
    u32 o = queue[q];
    u32 v = o / TBsz, tb = o % TBsz;
    double a0=0, a1=0, a2=0, a3=0;
    for (int w = 0; w < NWH; ++w) {
      u64 mw = hbits[(size_t)tb*NWH + w];
      for (int j = 0; j < 64; j += 4) {
        if ((mw >> (j+0)) & 1ull) a0 += (double)W[(size_t)(w*64+j+0)*NV + v];
        if ((mw >> (j+1)) & 1ull) a1 += (double)W[(size_t)(w*64+j+1)*NV + v];
        if ((mw >> (j+2)) & 1ull) a2 += (double)W[(size_t)(w*64+j+2)*NV + v];
        if ((mw >> (j+3)) & 1ull) a3 += (double)W[(size_t)(w*64+j+3)*NV + v];
      }
    }
    double p = sigmoid64(((a0+a1)+(a2+a3)) + (double)bv[v]);
    double u = tf_uniform64(k0, k1, o);
    unsigned smp = (u < p) ? 1u : 0u;
    if (vf) vf[o] = (float)smp;
    if (fixbits) {
      size_t wi = (size_t)tb*NWV + (v >> 6);
      unsigned bit = v & 63u;
      unsigned cur = (unsigned)((fixbits[wi] >> bit) & 1ull);
      if (cur != smp) atomicXor(&fixbits[wi], 1ull << bit);
    }
  }
}

// ---------------- h-side exact fixup (f64) --------------------------------------
__global__ __launch_bounds__(256) void khid_fix(
    const u64* __restrict__ vbits, const float* __restrict__ W,
    const double* __restrict__ U64, const float* __restrict__ bh,
    const float* __restrict__ binit, const double* __restrict__ rT,
    u64* __restrict__ fixbits, const u32* __restrict__ queue,
    const u32* __restrict__ cnt, u32 k0, u32 k1) {
  u32 n = *cnt; if (n > QCAP) n = QCAP;
  for (u32 q = blockIdx.x*256 + threadIdx.x; q < n; q += gridDim.x*256) {
    u32 o = queue[q];
    u32 h = o / TBsz, tb = o % TBsz;
    u32 t = tb / BB, b = tb % BB;
    double a0=0, a1=0, a2=0, a3=0;
    for (int w = 0; w < NWV; ++w) {
      u64 mw = vbits[(size_t)tb*NWV + w];
      for (int j = 0; j < 64; j += 4) {
        if ((mw >> (j+0)) & 1ull) a0 += (double)W[(size_t)h*NV + w*64+j+0];
        if ((mw >> (j+1)) & 1ull) a1 += (double)W[(size_t)h*NV + w*64+j+1];
        if ((mw >> (j+2)) & 1ull) a2 += (double)W[(size_t)h*NV + w*64+j+2];
        if ((mw >> (j+3)) & 1ull) a3 += (double)W[(size_t)h*NV + w*64+j+3];
      }
    }
    double logit = (a0+a1) + (a2+a3);
    if (t > 0) {
      const double* __restrict__ rp = rT + ((size_t)(t-1)*BB + b)*NH;
      const double* __restrict__ Ur = U64 + (size_t)h*NH;
      double u0=0, u1=0, u2=0, u3=0;
      for (int r = 0; r < NH; r += 4) {
        u0 = fma(Ur[r+0], rp[r+0], u0);
        u1 = fma(Ur[r+1], rp[r+1], u1);
        u2 = fma(Ur[r+2], rp[r+2], u2);
        u3 = fma(Ur[r+3], rp[r+3], u3);
      }
      logit = (logit + ((u0+u1)+(u2+u3))) + (double)bh[h];
    } else {
      logit += (double)binit[h];
    }
    double p = sigmoid64(logit);
    double u = tf_uniform64(k0, k1, o);
    unsigned smp = (u < p) ? 1u : 0u;
    size_t wi = (size_t)tb*NWH + (h >> 6);
    unsigned bit = h & 63u;
    unsigned cur = (unsigned)((fixbits[wi] >> bit) & 1ull);
    if (cur != smp) atomicXor(&fixbits[wi], 1ull << bit);
  }
}

extern "C" void kernel_launch(void* const* d_in, const int* in_sizes, int n_in,
                              void* d_out, int out_size, void* d_ws, size_t ws_size,
                              hipStream_t stream) {
  const float* vd    = (const float*)d_in[0];
  const float* W     = (const float*)d_in[1];
  const float* U     = (const float*)d_in[2];
  const float* bh    = (const float*)d_in[3];
  const float* binit = (const float*)d_in[4];
  const float* bv    = (const float*)d_in[5];

  float* out_v = (float*)d_out;            // (V,T,B) final samples (written last)
  float* out_r = (float*)d_out + VTBsz;    // (H,T,B) r_data f32
  double* WvT = (double*)d_out;            // aliases out_v region; dead by final kvisM

  // ws layout (~171 MB)
  char* w = (char*)d_ws;
  double* rT    = (double*)w;  w += (size_t)HTBsz*8;        // 134.2 MB, [t][b][h]
  u64* vdbits   = (u64*)w;     w += (size_t)TBsz*NWV*8;     // 4 MB
  u64* v1bits   = (u64*)w;     w += (size_t)TBsz*NWV*8;     // 4 MB
  u64* h1bits   = (u64*)w;     w += (size_t)TBsz*NWH*8;     // 2 MB
  u64* h2bits   = (u64*)w;     w += (size_t)TBsz*NWH*8;     // 2 MB
  double* W64   = (double*)w;  w += (size_t)NH*NV*8;        // 4 MB
  double* U64   = (double*)w;  w += (size_t)NH*NH*8;        // 2 MB
  float4* UB    = (float4*)w;  w += (size_t)NH*NH*4;        // 1 MB
  ushort* A1    = (ushort*)w;  w += (size_t)NH*NV*2;        // 1 MB
  ushort* A2    = (ushort*)w;  w += (size_t)NH*NV*2;        // 1 MB
  ushort* AW1   = (ushort*)w;  w += (size_t)NH*NV*2;        // 1 MB
  ushort* AW2   = (ushort*)w;  w += (size_t)NH*NV*2;        // 1 MB
  ushort* AU1   = (ushort*)w;  w += (size_t)NH*NH*2;        // 0.5 MB
  ushort* AU2   = (ushort*)w;  w += (size_t)NH*NH*2;        // 0.5 MB
  u32* q0       = (u32*)w;     w += (size_t)QCAP*4;         // 4 MB
  u32* q1       = (u32*)w;     w += (size_t)QCAP*4;         // 4 MB
  u32* q2       = (u32*)w;     w += (size_t)QCAP*4;         // 4 MB
  u32* cnt      = (u32*)w;     w += 256;
  (void)ws_size; (void)in_sizes; (void)n_in; (void)out_size;

  // host-side key derivation (jax.random.key(42), partitionable threefry splits)
  uint32_t ka0,ka1, sk0,sk1;
  tf2x32(0u,42u, 0u,0u, ka0,ka1);
  tf2x32(0u,42u, 0u,1u, sk0,sk1);
  uint32_t kb0,kb1, k10,k11, k20,k21;
  tf2x32(ka0,ka1, 0u,0u, kb0,kb1);
  tf2x32(ka0,ka1, 0u,1u, k10,k11);
  tf2x32(ka0,ka1, 0u,2u, k20,k21);
  uint32_t kc0,kc1, kf0,kf1;
  tf2x32(kb0,kb1, 0u,0u, kc0,kc1);
  tf2x32(kb0,kb1, 0u,1u, kf0,kf1);

  hipMemsetAsync(cnt, 0, 3*sizeof(u32), stream);

  // 0) fused preps
  kprepWall<<<(NH*NV)/256, 256, 0, stream>>>(W, W64, A1, A2, AW1, AW2);
  kprepUall<<<(NH*NH)/256, 256, 0, stream>>>(U, U64, UB, AU1, AU2);
  kpack_f32<<<2048, 256, 0, stream>>>(vd, vdbits);

  // 1) WvT = (W @ v_data)^T  (f64, broadcast-W R12 structure)
  kWv<<<TT*(NH/8), 256, 0, stream>>>(vdbits, W64, WvT);

  // 2) fused mean-field recurrence (R8-proven structure)
  krecur<<<BB, NH, 0, stream>>>(WvT, UB, bh, binit, rT);

  // 2b) out_r transpose + h1 = bernoulli(sk, r) fused
  ktrans_s<<<dim3(TT, NH/32, BB/32), 256, 0, stream>>>(rT, out_r,
                                                       (uint8_t*)h1bits, sk0, sk1);

  // 3) v1 = bernoulli(k1, sigmoid(W^T h1 + bv)) : bf16-MFMA fast + f64 fix
  kvisM<<<TBsz/128, 256, 0, stream>>>(A1, A2, bv, h1bits, v1bits, nullptr,
                                      q0, cnt+0, k10, k11);
  kvis_fix<<<256, 256, 0, stream>>>(W, bv, h1bits, v1bits, nullptr,
                                    q0, cnt+0, k10, k11);

  // 4) h2 = bernoulli(k2, sigmoid(W v1 + U r_lag + bias)) : bf16-MFMA + f64 fix
  khidM<<<8*512, 256, 0, stream>>>(AW1, AW2, AU1, AU2, bh, binit,
                                   v1bits, out_r, h2bits, q1, cnt+1, k20, k21);
  khid_fix<<<256, 256, 0, stream>>>(v1bits, W, U64, bh, binit, rT,
                                    h2bits, q1, cnt+1, k20, k21);

  // 5) v_model = bernoulli(kf, sigmoid(W^T h2 + bv)) -> out_v
  kvisM<<<TBsz/128, 256, 0, stream>>>(A1, A2, bv, h2bits, nullptr, out_v,
                                      q2, cnt+2, kf0, kf1);
  kvis_fix<<<256, 256, 0, stream>>>(W, bv, h2bits, nullptr, out_v,
                                    q2, cnt+2, kf0, kf1);
}